// Round 4
// baseline (210.346 us; speedup 1.0000x reference)
//
#include <hip/hip_runtime.h>

#define C_CH  256
#define H_FM  200
#define W_FM  200
#define N_BOX 1024
#define OHp   7
#define OWp   7
#define NG    16                      // channel groups (16 x 16ch: per-XCD L2-resident slices)
#define CG    16                      // channels per group
#define CGP   17                      // padded LDS channel stride
#define NCHUNK 25                     // h chunks of 8 rows
#define CHROWS 8
#define GSTRIDE (H_FM * W_FM * CG)    // 640,000 floats per group slice (2.56 MB)
#define HSTRIDE (W_FM * CG)           // 3,200 floats per h row (within group)
#define AUXG    (NCHUNK * HSTRIDE)    // 80,000 floats per group aux slice (0.32 MB)
#define GPAD  17                      // pool grid LDS stride (floats)
#define TW    40                      // w-strip width in fused scan
#define NWT   5                       // strips per row (200/40)

// ============================================================================
// Layouts:
//   T2[g16][h][w][cg]   : w-scanned AND h-scanned within 8-row chunks.
//   aux2[g16][ch][w][cg]: chunk totals -> exclusive offsets (closer-scanned).
// Final integral image (1-based r,k):
//   II(r,k)[c] = T2[g][r-1][k-1][cg] + aux2[g][(r-1)>>3][k-1][cg];  II(0,*)=0
// Channel mapping: c = g16*16 + cg.
//
// Round-3 postmortem: top-5 = five 268MB harness poison fills @42+us; our 3
// kernels each <42.4 -> sum <127 < dur_us=135.5 -> timed region includes
// ~2 fills (~85us fixed). Kernel budget is ~48us vs ~30us floor. This round:
// remove the aux_scan dispatch+gap by folding it into fused_scan via a
// per-group closer block (stream-K pattern, device-scope fence + atomic).
// ============================================================================

// Per-group completion counters. Zero at module load; each closer re-arms its
// own slot to 0 after use, so every timed iteration (graph replay) starts
// clean without a memset dispatch. Not affected by workspace re-poison.
__device__ int g_cnt[NG];

// ----------------------------------------------------------------------------
// K12 fused: one block = (8-row chunk, 16-ch group). Grid (25,16) = 400 blocks.
// Reads fm once; w-scan (register carry across 5 strips) + intra-chunk
// vertical cumsum in LDS; writes chunk-scanned T2 + aux totals. The LAST
// block to finish in each group exclusive-scans that group's aux in place
// (identical add order to the old aux_scan_kernel -> bitwise-same results).
// ----------------------------------------------------------------------------
__global__ __launch_bounds__(256) void fused_scan_kernel(const float* __restrict__ fm,
                                                         float* __restrict__ T2,
                                                         float* __restrict__ aux2) {
    __shared__ float tile[CHROWS][TW][CGP];   // 21.76 KB
    __shared__ int isLast;
    const int t  = threadIdx.x;
    const int ch = blockIdx.x;                // 0..24
    const int g  = blockIdx.y;                // 0..15
    const int h0 = ch * CHROWS;
    const float* fmg = fm + (size_t)(g * CG) * (H_FM * W_FM) + (size_t)h0 * W_FM;

    // per-thread load/LDS descriptors: f = s*256+t over 1280 float4 per strip
    //   ci = f/80 (channel 0..15), r = (f%80)/10 (row 0..7), w4 = f%10
    // consecutive lanes -> w4-contiguous 160 B runs in fm (coalesced)
    const float* gp[5];
    int lo[5];
    #pragma unroll
    for (int s = 0; s < 5; ++s) {
        int f   = s * 256 + t;
        int ci  = f / 80;
        int rem = f - ci * 80;
        int r   = rem / 10;
        int w4  = rem - r * 10;
        gp[s] = fmg + (size_t)ci * (H_FM * W_FM) + r * W_FM + w4 * 4;
        lo[s] = (r * TW + w4 * 4) * CGP + ci;
    }

    const int cg = t & 15;                    // w-scan channel
    const int rr = t >> 4;                    // w-scan row (0..7 active)
    float accw = 0.0f;                        // w-scan carry across strips
    float4 stage[5];

    #pragma unroll
    for (int s = 0; s < 5; ++s) stage[s] = *(const float4*)(gp[s]);

    for (int wt = 0; wt < NWT; ++wt) {
        // ---- regs -> LDS (transpose to [r][w][cg])
        #pragma unroll
        for (int s = 0; s < 5; ++s) {
            float4 v = stage[s];
            float* p = &tile[0][0][0] + lo[s];
            p[0]       = v.x;
            p[CGP]     = v.y;
            p[2 * CGP] = v.z;
            p[3 * CGP] = v.w;
        }
        __syncthreads();

        // ---- prefetch next strip NOW; in flight during the w-scan phase
        if (wt + 1 < NWT) {
            #pragma unroll
            for (int s = 0; s < 5; ++s)
                stage[s] = *(const float4*)(gp[s] + (wt + 1) * TW);
        }

        // ---- w-scan: thread (rr, cg), 128 active, serial along w, reg carry
        if (t < CHROWS * CG) {
            #pragma unroll
            for (int w = 0; w < TW; ++w) {
                accw += tile[rr][w][cg];
                tile[rr][w][cg] = accw;
            }
        }
        __syncthreads();

        // ---- vertical cumsum over 8 rows + direct store (640 cols/strip)
        float* dstT = T2 + (size_t)g * GSTRIDE;
        float* dstA = aux2 + (size_t)g * AUXG + (size_t)ch * HSTRIDE;
        #pragma unroll
        for (int k = 0; k < 3; ++k) {
            int col = k * 256 + t;            // 0..639 = (w, cc)
            if (col < TW * CG) {
                int w   = col >> 4;
                int cc  = col & 15;
                float vacc = 0.0f;
                float* dcol = dstT + (size_t)(wt * TW + w) * CG + cc;
                #pragma unroll
                for (int r = 0; r < CHROWS; ++r) {
                    vacc += tile[r][w][cc];
                    dcol[(size_t)(h0 + r) * HSTRIDE] = vacc;
                }
                dstA[(size_t)(wt * TW + w) * CG + cc] = vacc;   // inclusive total
            }
        }
        __syncthreads();                       // LDS reusable for next strip
    }

    // ---- closer: last block of this group exclusive-scans aux2[g] in place.
    // release: every thread drains+publishes its stores, then one atomic.
    __threadfence();
    __syncthreads();
    if (t == 0) {
        int old = atomicAdd(&g_cnt[g], 1);
        isLast = (old == NCHUNK - 1);
    }
    __syncthreads();
    if (!isLast) return;

    __threadfence();                           // acquire: see all blocks' aux
    if (t == 0) atomicExch(&g_cnt[g], 0);      // re-arm for next graph replay

    // 800 float4 columns; wave reads/writes 1 KB contiguous per chunk row.
    float4* basep = (float4*)aux2 + (size_t)g * (AUXG / 4);
    for (int c0 = t; c0 < HSTRIDE / 4; c0 += 256) {
        float4* p = basep + c0;
        float4 acc = make_float4(0.f, 0.f, 0.f, 0.f);
        #pragma unroll
        for (int cq = 0; cq < NCHUNK; ++cq) {
            float4 v = p[(size_t)cq * (HSTRIDE / 4)];
            p[(size_t)cq * (HSTRIDE / 4)] = acc;
            acc.x += v.x; acc.y += v.y; acc.z += v.z; acc.w += v.w;
        }
    }
}

// ----------------------------------------------------------------------------
// K4: pool8. 16384 blocks; block = (box n, group g16) with g16 = (bx&7) +
// 8*(bx/8192) -> XCD-resident slice gathers.
// ----------------------------------------------------------------------------
__global__ __launch_bounds__(256) void pool8_kernel(const float* __restrict__ T2,
                                                    const float* __restrict__ aux2,
                                                    const float* __restrict__ boxes,
                                                    float* __restrict__ out) {
    __shared__ float grid[196][GPAD];
    __shared__ int er[14];                 // rows: rs[0..6], re[0..6]
    __shared__ int ec[14];                 // cols: cs[0..6], ce[0..6]
    __shared__ float rcpA[49];
    const int bx   = blockIdx.x;
    const int half = bx >> 13;             // 0 or 1
    const int wi   = bx & 8191;
    const int n    = wi >> 3;
    const int g    = (wi & 7) + half * 8;  // g16; XCD bx%8 serves one slice/half
    const int t    = threadIdx.x;

    const float4 box = ((const float4*)boxes)[n];
    int b0 = (int)floorf(box.x * 0.25f);
    int b1 = (int)floorf(box.y * 0.25f);
    int b2 = (int)floorf(box.z * 0.25f);
    int b3 = (int)floorf(box.w * 0.25f);
    int x1 = min(max(b0, 0), W_FM - 1);
    int y1 = min(max(b1, 0), H_FM - 1);
    int x2 = min(max(b2 + 1, x1 + 1), W_FM);
    int y2 = min(max(b3 + 1, y1 + 1), H_FM);
    int rh = y2 - y1;
    int rw = x2 - x1;

    // ---- edge precompute
    if (t < 14) {
        er[t] = (t < 7) ? (y1 + (t * rh) / OHp)
                        : (y1 + ((t - 6) * rh + OHp - 1) / OHp);
    } else if (t >= 64 && t < 78) {
        int u = t - 64;
        ec[u] = (u < 7) ? (x1 + (u * rw) / OWp)
                        : (x1 + ((u - 6) * rw + OWp - 1) / OWp);
    }
    __syncthreads();

    // ---- 49 reciprocal areas (uses er/ec; published by the phase-1 barrier)
    if (t < 49) {
        int i = t / 7;
        int j = t - i * 7;
        rcpA[t] = 1.0f / (float)((er[7 + i] - er[i]) * (ec[7 + j] - ec[j]));
    }

    // ---- phase 1: grid load (positions deduped; edges from LDS)
    {
        const int c4 = t & 3;              // float4 slot within 16 channels
        const int p0 = t >> 2;             // 0..63 positions per iteration
        const float* Tg = T2   + (size_t)g * GSTRIDE + c4 * 4;
        const float* Ag = aux2 + (size_t)g * AUXG   + c4 * 4;
        #pragma unroll
        for (int it = 0; it < 4; ++it) {
            int pos = it * 64 + p0;
            if (pos < 196) {
                int ri = pos / 14;
                int ci = pos - ri * 14;
                int r = er[ri];
                int k = ec[ci];
                float4 v = make_float4(0.f, 0.f, 0.f, 0.f);
                if (r > 0 && k > 0) {
                    float4 tv = *(const float4*)(Tg + ((size_t)(r - 1) * W_FM + (k - 1)) * CG);
                    float4 av = *(const float4*)(Ag + ((size_t)((r - 1) >> 3) * W_FM + (k - 1)) * CG);
                    v.x = tv.x + av.x; v.y = tv.y + av.y;
                    v.z = tv.z + av.z; v.w = tv.w + av.w;
                }
                grid[pos][c4 * 4 + 0] = v.x;
                grid[pos][c4 * 4 + 1] = v.y;
                grid[pos][c4 * 4 + 2] = v.z;
                grid[pos][c4 * 4 + 3] = v.w;
            }
        }
    }
    __syncthreads();

    // ---- phase 2: compute + direct coalesced store (784 floats/block)
    float* dst = out + (size_t)n * (C_CH * 49) + (size_t)g * (CG * 49);
    #pragma unroll
    for (int k = 0; k < 4; ++k) {
        int flat = k * 256 + t;            // 0..783
        if (flat < CG * 49) {
            int cg  = flat / 49;
            int rem = flat - cg * 49;
            int i = rem / 7;
            int j = rem - i * 7;
            float a = grid[(7 + i) * 14 + 7 + j][cg];   // II(re, ce)
            float b = grid[i * 14 + 7 + j][cg];         // II(rs, ce)
            float c = grid[(7 + i) * 14 + j][cg];       // II(re, cs)
            float d = grid[i * 14 + j][cg];             // II(rs, cs)
            dst[flat] = ((a - b) - (c - d)) * rcpA[rem];
        }
    }
}

// ============================================================================
// FALLBACK PATH — used only if workspace is too small.
// ============================================================================
__device__ __forceinline__ void box_edges(const float4 box, int i, int j,
                                          int& rs, int& re, int& cs, int& ce) {
    int b0 = (int)floorf(box.x * 0.25f);
    int b1 = (int)floorf(box.y * 0.25f);
    int b2 = (int)floorf(box.z * 0.25f);
    int b3 = (int)floorf(box.w * 0.25f);
    int x1 = min(max(b0, 0), W_FM - 1);
    int y1 = min(max(b1, 0), H_FM - 1);
    int x2 = min(max(b2 + 1, x1 + 1), W_FM);
    int y2 = min(max(b3 + 1, y1 + 1), H_FM);
    int rh = y2 - y1;
    int rw = x2 - x1;
    rs = y1 + (i * rh) / OHp;
    re = y1 + ((i + 1) * rh + OHp - 1) / OHp;
    cs = x1 + (j * rw) / OWp;
    ce = x1 + ((j + 1) * rw + OWp - 1) / OWp;
}

__global__ __launch_bounds__(256) void pool_direct_kernel(const float* __restrict__ fm,
                                                          const float* __restrict__ boxes,
                                                          float* __restrict__ out) {
    const int idx = blockIdx.x * 256 + threadIdx.x;
    const int j  = idx % OWp;
    const int t1 = idx / OWp;
    const int i  = t1 % OHp;
    const int t2 = t1 / OHp;
    const int c  = t2 % C_CH;
    const int n  = t2 / C_CH;

    const float4 box = ((const float4*)boxes)[n];
    int rs, re, cs, ce;
    box_edges(box, i, j, rs, re, cs, ce);

    const float* base = fm + (size_t)c * (H_FM * W_FM);
    float sum = 0.0f;
    for (int r = rs; r < re; ++r) {
        const float* rowp = base + (size_t)r * W_FM;
        for (int k = cs; k < ce; ++k) sum += rowp[k];
    }
    float area = (float)((re - rs) * (ce - cs));
    out[idx] = sum / area;
}

// ---------------------------------------------------------------------------
extern "C" void kernel_launch(void* const* d_in, const int* in_sizes, int n_in,
                              void* d_out, int out_size, void* d_ws, size_t ws_size,
                              hipStream_t stream) {
    const float* fm    = (const float*)d_in[0];   // [1,256,200,200] f32
    const float* boxes = (const float*)d_in[1];   // [1024,4] f32
    float* out = (float*)d_out;                   // [1024,256,7,7] f32

    const size_t tBytes   = (size_t)NG * GSTRIDE * sizeof(float);     // 40.96 MB
    const size_t auxBytes = (size_t)NG * AUXG * sizeof(float);        // 5.12 MB
    const int    total    = N_BOX * C_CH * OHp * OWp;
    const int    blocks   = total / 256;

    if (ws_size >= tBytes + auxBytes) {
        float* T2   = (float*)d_ws;
        float* aux2 = (float*)((char*)d_ws + tBytes);
        fused_scan_kernel<<<dim3(NCHUNK, NG), 256, 0, stream>>>(fm, T2, aux2);
        pool8_kernel<<<N_BOX * NG, 256, 0, stream>>>(T2, aux2, boxes, out);
    } else {
        pool_direct_kernel<<<blocks, 256, 0, stream>>>(fm, boxes, out);
    }
}

// Round 5
// 131.421 us; speedup vs baseline: 1.6006x; 1.6006x over previous
//
#include <hip/hip_runtime.h>

#define C_CH  256
#define H_FM  200
#define W_FM  200
#define N_BOX 1024
#define OHp   7
#define OWp   7
#define NG    16                      // channel groups (16 x 16ch: per-XCD L2-resident slices)
#define CG    16                      // channels per group
#define CGP   17                      // padded LDS channel stride
#define NCHUNK 25                     // h chunks of 8 rows
#define CHROWS 8
#define GSTRIDE (H_FM * W_FM * CG)    // 640,000 floats per group slice (2.56 MB)
#define HSTRIDE (W_FM * CG)           // 3,200 floats per h row (within group)
#define AUXG    (NCHUNK * HSTRIDE)    // 80,000 floats per group aux slice (0.32 MB)
#define GPAD  17                      // pool grid LDS stride (floats)
#define TW    40                      // w-strip width in fused scan
#define NWT   5                       // strips per row (200/40)

// ============================================================================
// Layouts:
//   T2[g16][h][w][cg]   : w-scanned AND h-scanned within 8-row chunks.
//   aux2[g16][ch][w][cg]: exclusive chunk offsets (aux_scan derives them from
//                         T2 rows 8ch+7 — the chunk totals — no aux writes
//                         needed in fused_scan).
// Final integral image (1-based r,k):
//   II(r,k)[c] = T2[g][r-1][k-1][cg] + aux2[g][(r-1)>>3][k-1][cg];  II(0,*)=0
// Channel mapping: c = g16*16 + cg.
//
// Round-4 postmortem: stream-K closer REVERTED — per-block __threadfence()
// (device scope) forces XCD-L2 writeback of the 46MB dirty working set ->
// fused_scan 97-112us (5x). Also decomposed the budget: two ~42.5us harness
// poison fills (~85us fixed) + fused+aux ~25us + pool8 ~20-23us.
// This round: r3 structure + (a) XOR bank-swizzle on the fused_scan LDS store
// phase (was 8-way, 1.79M conflict cycles), (b) aux derived from T2 (-5MB).
//
// LDS swizzle: physical channel slot = ci ^ (w>>2) (bijective on 0..15; w is
// strip-local). Store phase: bank = 8r + 4w4 + (ci^w4) -> ~2-way (was 8 banks
// for 64 lanes). w-scan / vertical phases: swizzle is constant within each
// instruction -> unchanged free <=2-way patterns.
// ============================================================================

// ----------------------------------------------------------------------------
// K12 fused: one block = (8-row chunk, 16-ch group). Grid (25,16) = 400 blocks.
// Reads fm once; w-scan (register carry across 5 strips) + intra-chunk
// vertical cumsum in LDS; writes chunk-scanned T2.
// ----------------------------------------------------------------------------
__global__ __launch_bounds__(256) void fused_scan_kernel(const float* __restrict__ fm,
                                                         float* __restrict__ T2) {
    __shared__ float tile[CHROWS][TW][CGP];   // 21.76 KB
    const int t  = threadIdx.x;
    const int ch = blockIdx.x;                // 0..24
    const int g  = blockIdx.y;                // 0..15
    const int h0 = ch * CHROWS;
    const float* fmg = fm + (size_t)(g * CG) * (H_FM * W_FM) + (size_t)h0 * W_FM;

    // per-thread load/LDS descriptors: f = s*256+t over 1280 float4 per strip
    //   ci = f/80 (channel 0..15), r = (f%80)/10 (row 0..7), w4 = f%10
    // consecutive lanes -> w4-contiguous 160 B runs in fm (coalesced)
    const float* gp[5];
    int lo[5];
    #pragma unroll
    for (int s = 0; s < 5; ++s) {
        int f   = s * 256 + t;
        int ci  = f / 80;
        int rem = f - ci * 80;
        int r   = rem / 10;
        int w4  = rem - r * 10;
        gp[s] = fmg + (size_t)ci * (H_FM * W_FM) + r * W_FM + w4 * 4;
        lo[s] = (r * TW + w4 * 4) * CGP + (ci ^ w4);      // bank swizzle
    }

    const int cg = t & 15;                    // w-scan channel
    const int rr = t >> 4;                    // w-scan row (0..7 active)
    float accw = 0.0f;                        // w-scan carry across strips
    float4 stage[5];

    #pragma unroll
    for (int s = 0; s < 5; ++s) stage[s] = *(const float4*)(gp[s]);

    for (int wt = 0; wt < NWT; ++wt) {
        // ---- regs -> LDS (transpose to [r][w][swz(ci)])
        #pragma unroll
        for (int s = 0; s < 5; ++s) {
            float4 v = stage[s];
            float* p = &tile[0][0][0] + lo[s];
            p[0]       = v.x;
            p[CGP]     = v.y;
            p[2 * CGP] = v.z;
            p[3 * CGP] = v.w;
        }
        __syncthreads();

        // ---- prefetch next strip NOW; in flight during the w-scan phase
        if (wt + 1 < NWT) {
            #pragma unroll
            for (int s = 0; s < 5; ++s)
                stage[s] = *(const float4*)(gp[s] + (wt + 1) * TW);
        }

        // ---- w-scan: thread (rr, cg), 128 active, serial along w, reg carry
        if (t < CHROWS * CG) {
            #pragma unroll
            for (int w = 0; w < TW; ++w) {
                accw += tile[rr][w][cg ^ (w >> 2)];
                tile[rr][w][cg ^ (w >> 2)] = accw;
            }
        }
        __syncthreads();

        // ---- vertical cumsum over 8 rows + direct store (640 cols/strip)
        float* dstT = T2 + (size_t)g * GSTRIDE;
        #pragma unroll
        for (int k = 0; k < 3; ++k) {
            int col = k * 256 + t;            // 0..639 = (w, cc)
            if (col < TW * CG) {
                int w   = col >> 4;
                int cc  = col & 15;
                int ccs = cc ^ (w >> 2);      // physical LDS slot
                float vacc = 0.0f;
                float* dcol = dstT + (size_t)(wt * TW + w) * CG + cc;
                #pragma unroll
                for (int r = 0; r < CHROWS; ++r) {
                    vacc += tile[r][w][ccs];
                    dcol[(size_t)(h0 + r) * HSTRIDE] = vacc;
                }
            }
        }
        __syncthreads();                       // LDS reusable for next strip
    }
}

// ----------------------------------------------------------------------------
// K3: exclusive scan of the 25 chunk totals. Chunk totals are read straight
// from T2 rows 8ch+7 (identical values/add-order to the old aux-write path).
// 200 blocks x 64 threads; one float4 column each.
// ----------------------------------------------------------------------------
__global__ __launch_bounds__(64) void aux_scan_kernel(const float* __restrict__ T2,
                                                      float* __restrict__ aux2) {
    const int idx = blockIdx.x * 64 + threadIdx.x;    // 0..12799
    const int g   = idx / (HSTRIDE / 4);
    const int r4  = idx - g * (HSTRIDE / 4);
    const float4* tp = (const float4*)T2 + (size_t)g * (GSTRIDE / 4)
                                         + (size_t)(CHROWS - 1) * (HSTRIDE / 4) + r4;
    float4* ap = (float4*)aux2 + (size_t)g * (AUXG / 4) + r4;
    float4 acc = make_float4(0.f, 0.f, 0.f, 0.f);
    #pragma unroll
    for (int cq = 0; cq < NCHUNK; ++cq) {
        float4 v = tp[(size_t)cq * (CHROWS * HSTRIDE / 4)];
        ap[(size_t)cq * (HSTRIDE / 4)] = acc;
        acc.x += v.x; acc.y += v.y; acc.z += v.z; acc.w += v.w;
    }
}

// ----------------------------------------------------------------------------
// K4: pool8. 16384 blocks; block = (box n, group g16) with g16 = (bx&7) +
// 8*(bx/8192) -> XCD-resident slice gathers (2.56+0.32 MB < 4 MB L2).
// ----------------------------------------------------------------------------
__global__ __launch_bounds__(256) void pool8_kernel(const float* __restrict__ T2,
                                                    const float* __restrict__ aux2,
                                                    const float* __restrict__ boxes,
                                                    float* __restrict__ out) {
    __shared__ float grid[196][GPAD];
    __shared__ int er[14];                 // rows: rs[0..6], re[0..6]
    __shared__ int ec[14];                 // cols: cs[0..6], ce[0..6]
    __shared__ float rcpA[49];
    const int bx   = blockIdx.x;
    const int half = bx >> 13;             // 0 or 1
    const int wi   = bx & 8191;
    const int n    = wi >> 3;
    const int g    = (wi & 7) + half * 8;  // g16; XCD bx%8 serves one slice/half
    const int t    = threadIdx.x;

    const float4 box = ((const float4*)boxes)[n];
    int b0 = (int)floorf(box.x * 0.25f);
    int b1 = (int)floorf(box.y * 0.25f);
    int b2 = (int)floorf(box.z * 0.25f);
    int b3 = (int)floorf(box.w * 0.25f);
    int x1 = min(max(b0, 0), W_FM - 1);
    int y1 = min(max(b1, 0), H_FM - 1);
    int x2 = min(max(b2 + 1, x1 + 1), W_FM);
    int y2 = min(max(b3 + 1, y1 + 1), H_FM);
    int rh = y2 - y1;
    int rw = x2 - x1;

    // ---- edge precompute
    if (t < 14) {
        er[t] = (t < 7) ? (y1 + (t * rh) / OHp)
                        : (y1 + ((t - 6) * rh + OHp - 1) / OHp);
    } else if (t >= 64 && t < 78) {
        int u = t - 64;
        ec[u] = (u < 7) ? (x1 + (u * rw) / OWp)
                        : (x1 + ((u - 6) * rw + OWp - 1) / OWp);
    }
    __syncthreads();

    // ---- 49 reciprocal areas (uses er/ec; published by the phase-1 barrier)
    if (t < 49) {
        int i = t / 7;
        int j = t - i * 7;
        rcpA[t] = 1.0f / (float)((er[7 + i] - er[i]) * (ec[7 + j] - ec[j]));
    }

    // ---- phase 1: grid load (positions deduped; edges from LDS)
    {
        const int c4 = t & 3;              // float4 slot within 16 channels
        const int p0 = t >> 2;             // 0..63 positions per iteration
        const float* Tg = T2   + (size_t)g * GSTRIDE + c4 * 4;
        const float* Ag = aux2 + (size_t)g * AUXG   + c4 * 4;
        #pragma unroll
        for (int it = 0; it < 4; ++it) {
            int pos = it * 64 + p0;
            if (pos < 196) {
                int ri = pos / 14;
                int ci = pos - ri * 14;
                int r = er[ri];
                int k = ec[ci];
                float4 v = make_float4(0.f, 0.f, 0.f, 0.f);
                if (r > 0 && k > 0) {
                    float4 tv = *(const float4*)(Tg + ((size_t)(r - 1) * W_FM + (k - 1)) * CG);
                    float4 av = *(const float4*)(Ag + ((size_t)((r - 1) >> 3) * W_FM + (k - 1)) * CG);
                    v.x = tv.x + av.x; v.y = tv.y + av.y;
                    v.z = tv.z + av.z; v.w = tv.w + av.w;
                }
                grid[pos][c4 * 4 + 0] = v.x;
                grid[pos][c4 * 4 + 1] = v.y;
                grid[pos][c4 * 4 + 2] = v.z;
                grid[pos][c4 * 4 + 3] = v.w;
            }
        }
    }
    __syncthreads();

    // ---- phase 2: compute + direct coalesced store (784 floats/block)
    float* dst = out + (size_t)n * (C_CH * 49) + (size_t)g * (CG * 49);
    #pragma unroll
    for (int k = 0; k < 4; ++k) {
        int flat = k * 256 + t;            // 0..783
        if (flat < CG * 49) {
            int cg  = flat / 49;
            int rem = flat - cg * 49;
            int i = rem / 7;
            int j = rem - i * 7;
            float a = grid[(7 + i) * 14 + 7 + j][cg];   // II(re, ce)
            float b = grid[i * 14 + 7 + j][cg];         // II(rs, ce)
            float c = grid[(7 + i) * 14 + j][cg];       // II(re, cs)
            float d = grid[i * 14 + j][cg];             // II(rs, cs)
            dst[flat] = ((a - b) - (c - d)) * rcpA[rem];
        }
    }
}

// ============================================================================
// FALLBACK PATH — used only if workspace is too small.
// ============================================================================
__device__ __forceinline__ void box_edges(const float4 box, int i, int j,
                                          int& rs, int& re, int& cs, int& ce) {
    int b0 = (int)floorf(box.x * 0.25f);
    int b1 = (int)floorf(box.y * 0.25f);
    int b2 = (int)floorf(box.z * 0.25f);
    int b3 = (int)floorf(box.w * 0.25f);
    int x1 = min(max(b0, 0), W_FM - 1);
    int y1 = min(max(b1, 0), H_FM - 1);
    int x2 = min(max(b2 + 1, x1 + 1), W_FM);
    int y2 = min(max(b3 + 1, y1 + 1), H_FM);
    int rh = y2 - y1;
    int rw = x2 - x1;
    rs = y1 + (i * rh) / OHp;
    re = y1 + ((i + 1) * rh + OHp - 1) / OHp;
    cs = x1 + (j * rw) / OWp;
    ce = x1 + ((j + 1) * rw + OWp - 1) / OWp;
}

__global__ __launch_bounds__(256) void pool_direct_kernel(const float* __restrict__ fm,
                                                          const float* __restrict__ boxes,
                                                          float* __restrict__ out) {
    const int idx = blockIdx.x * 256 + threadIdx.x;
    const int j  = idx % OWp;
    const int t1 = idx / OWp;
    const int i  = t1 % OHp;
    const int t2 = t1 / OHp;
    const int c  = t2 % C_CH;
    const int n  = t2 / C_CH;

    const float4 box = ((const float4*)boxes)[n];
    int rs, re, cs, ce;
    box_edges(box, i, j, rs, re, cs, ce);

    const float* base = fm + (size_t)c * (H_FM * W_FM);
    float sum = 0.0f;
    for (int r = rs; r < re; ++r) {
        const float* rowp = base + (size_t)r * W_FM;
        for (int k = cs; k < ce; ++k) sum += rowp[k];
    }
    float area = (float)((re - rs) * (ce - cs));
    out[idx] = sum / area;
}

// ---------------------------------------------------------------------------
extern "C" void kernel_launch(void* const* d_in, const int* in_sizes, int n_in,
                              void* d_out, int out_size, void* d_ws, size_t ws_size,
                              hipStream_t stream) {
    const float* fm    = (const float*)d_in[0];   // [1,256,200,200] f32
    const float* boxes = (const float*)d_in[1];   // [1024,4] f32
    float* out = (float*)d_out;                   // [1024,256,7,7] f32

    const size_t tBytes   = (size_t)NG * GSTRIDE * sizeof(float);     // 40.96 MB
    const size_t auxBytes = (size_t)NG * AUXG * sizeof(float);        // 5.12 MB
    const int    total    = N_BOX * C_CH * OHp * OWp;
    const int    blocks   = total / 256;

    if (ws_size >= tBytes + auxBytes) {
        float* T2   = (float*)d_ws;
        float* aux2 = (float*)((char*)d_ws + tBytes);
        fused_scan_kernel<<<dim3(NCHUNK, NG), 256, 0, stream>>>(fm, T2);
        aux_scan_kernel<<<200, 64, 0, stream>>>(T2, aux2);
        pool8_kernel<<<N_BOX * NG, 256, 0, stream>>>(T2, aux2, boxes, out);
    } else {
        pool_direct_kernel<<<blocks, 256, 0, stream>>>(fm, boxes, out);
    }
}